// Round 1
// baseline (793.736 us; speedup 1.0000x reference)
//
#include <hip/hip_runtime.h>
#include <hip/hip_bf16.h>
#include <math.h>

#define HH 16
#define SS 2048
#define BBATCH 2
#define NROWS 4096   // B*S

typedef __attribute__((ext_vector_type(8))) __bf16 bf16x8;
typedef __attribute__((ext_vector_type(4))) float f32x4;
typedef const __attribute__((address_space(1))) unsigned int* gas1_t;
typedef __attribute__((address_space(3))) unsigned int* las3_t;

__device__ __forceinline__ unsigned short f2bf(float f) {
  unsigned u = __builtin_bit_cast(unsigned, f);
  u += 0x7fffu + ((u >> 16) & 1u);
  return (unsigned short)(u >> 16);
}

__device__ __forceinline__ void gload16(const void* g, void* l) {
  __builtin_amdgcn_global_load_lds((gas1_t)g, (las3_t)l, 16, 0, 0);
}
__device__ __forceinline__ f32x4 mfma16(bf16x8 a, bf16x8 b, f32x4 c) {
  return __builtin_amdgcn_mfma_f32_16x16x32_bf16(a, b, c, 0, 0, 0);
}

// ---------------- f32 -> bf16 copy (same layout) ----------------
__global__ __launch_bounds__(256) void k_convert(const float* __restrict__ in,
                                                 unsigned short* __restrict__ out, long n4) {
  long i = (long)blockIdx.x * blockDim.x + threadIdx.x;
  long stride = (long)gridDim.x * blockDim.x;
  for (; i < n4; i += stride) {
    float4 v = ((const float4*)in)[i];
    ushort4 o = { f2bf(v.x), f2bf(v.y), f2bf(v.z), f2bf(v.w) };
    ((ushort4*)out)[i] = o;
  }
}

// ---------------- W (K,N) f32 -> Wt (Npad,K) bf16 ----------------
__global__ __launch_bounds__(256) void k_transpose(const float* __restrict__ W,
                                                   unsigned short* __restrict__ Wt,
                                                   int K, int N, int Npad) {
  __shared__ float tile[32][33];
  int n0 = blockIdx.x * 32, k0 = blockIdx.y * 32;
  int tx = threadIdx.x & 31, ty = threadIdx.x >> 5;
  for (int i = ty; i < 32; i += 8) {
    int k = k0 + i, n = n0 + tx;
    tile[i][tx] = (k < K && n < N) ? W[(long)k * N + n] : 0.f;
  }
  __syncthreads();
  for (int i = ty; i < 32; i += 8) {
    int n = n0 + i, k = k0 + tx;
    if (n < Npad && k < K) Wt[(long)n * K + k] = f2bf(tile[tx][i]);
  }
}

// ---------------- GEMM: C(M,N) f32 = A(M,K)bf16 * Bt(Npad,K)bf16 + bias ----------------
__global__ __launch_bounds__(256) void k_gemm(const unsigned short* __restrict__ A,
                                              const unsigned short* __restrict__ Bt,
                                              const float* __restrict__ bias,
                                              float* __restrict__ C,
                                              int M, int N, int K) {
  __shared__ unsigned short lA[128 * 32];
  __shared__ unsigned short lB[128 * 32];
  int tid = threadIdx.x;
  int wave = tid >> 6, lane = tid & 63;
  int l15 = lane & 15, lhi = lane >> 4;
  int ntn = (N + 127) >> 7;
  int tm = blockIdx.x / ntn, tn = blockIdx.x % ntn;
  long row0 = (long)tm * 128, col0 = (long)tn * 128;
  int wr = wave >> 1, wc = wave & 1;

  const unsigned short* gA = A + (row0 + (tid >> 2)) * K + (tid & 3) * 8;
  const unsigned short* gB = Bt + (col0 + (tid >> 2)) * K + (tid & 3) * 8;
  unsigned short* lA0 = &lA[tid * 8];
  unsigned short* lB0 = &lB[tid * 8];

  f32x4 acc[4][4] = {};
  for (int k0 = 0; k0 < K; k0 += 32) {
    __syncthreads();
    gload16(gA + k0, lA0);
    gload16(gA + (long)64 * K + k0, lA0 + 2048);
    gload16(gB + k0, lB0);
    gload16(gB + (long)64 * K + k0, lB0 + 2048);
    asm volatile("s_waitcnt vmcnt(0)" ::: "memory");
    __syncthreads();
    bf16x8 af[4], bfr[4];
#pragma unroll
    for (int i = 0; i < 4; ++i) {
      af[i]  = *(const bf16x8*)&lA[(wr * 64 + i * 16 + l15) * 32 + lhi * 8];
      bfr[i] = *(const bf16x8*)&lB[(wc * 64 + i * 16 + l15) * 32 + lhi * 8];
    }
#pragma unroll
    for (int i = 0; i < 4; ++i)
#pragma unroll
      for (int j = 0; j < 4; ++j)
        acc[i][j] = mfma16(af[i], bfr[j], acc[i][j]);
  }
#pragma unroll
  for (int i = 0; i < 4; ++i)
#pragma unroll
    for (int j = 0; j < 4; ++j) {
      long r = row0 + wr * 64 + i * 16 + lhi * 4;
      long c = col0 + wc * 64 + j * 16 + l15;
      if (c < N) {
        float bv = bias[c];
#pragma unroll
        for (int rr = 0; rr < 4; ++rr)
          C[(r + rr) * N + c] = acc[i][j][rr] + bv;
      }
    }
}

// ---------------- RMSNorm: f32 (rows, ldx) -> bf16 (rows, L) ----------------
__global__ __launch_bounds__(256) void k_rmsnorm(const float* __restrict__ X,
                                                 const float* __restrict__ w,
                                                 unsigned short* __restrict__ Y,
                                                 int L, int ldx) {
  long row = blockIdx.x;
  const float* x = X + row * ldx;
  float ss = 0.f;
  int n4 = L >> 2;
  for (int i = threadIdx.x; i < n4; i += 256) {
    float4 v = ((const float4*)x)[i];
    ss += v.x * v.x + v.y * v.y + v.z * v.z + v.w * v.w;
  }
  for (int off = 32; off > 0; off >>= 1) ss += __shfl_xor(ss, off);
  __shared__ float sb[4];
  if ((threadIdx.x & 63) == 0) sb[threadIdx.x >> 6] = ss;
  __syncthreads();
  float scale = rsqrtf((sb[0] + sb[1] + sb[2] + sb[3]) / (float)L + 1e-6f);
  unsigned short* y = Y + row * L;
  for (int i = threadIdx.x; i < L; i += 256)
    y[i] = f2bf(x[i] * scale * w[i]);
}

// ---------------- q (NROWS,3072) f32 -> qf (B*H, S, 192) bf16, rope+scale ----------------
__global__ __launch_bounds__(256) void k_extract_q(const float* __restrict__ q,
                                                   unsigned short* __restrict__ qf) {
  int idx = blockIdx.x * 4 + (threadIdx.x >> 6);   // (b*S+s)*H + h
  int lane = threadIdx.x & 63;
  int h = idx & 15;
  int bs = idx >> 4;
  int s = bs & (SS - 1);
  const float* src = q + (long)idx * 192;
  long bh = (long)(bs >> 11) * HH + h;
  unsigned short* dst = qf + (bh * SS + s) * 192;
  const float scq = 0.07216878364870322f;  // 192^-0.5
  dst[lane]      = f2bf(src[lane] * scq);
  dst[lane + 64] = f2bf(src[lane + 64] * scq);
  if (lane < 32) {
    float inv = powf(10000.f, -(float)lane / 32.f);
    float ang = (float)s * inv;
    float sn, cs;
    sincosf(ang, &sn, &cs);
    float t1 = src[128 + lane], t2 = src[160 + lane];
    dst[128 + lane] = f2bf((t1 * cs - t2 * sn) * scq);
    dst[160 + lane] = f2bf((t2 * cs + t1 * sn) * scq);
  }
}

// ---------------- kvd rope cols (512..575) -> kf[...,128:192] broadcast over heads ----------------
__global__ __launch_bounds__(64) void k_extract_krope(const float* __restrict__ kvd,
                                                      unsigned short* __restrict__ kf) {
  int bs = blockIdx.x;
  int lane = threadIdx.x;
  int s = bs & (SS - 1), b = bs >> 11;
  const float* src = kvd + (long)bs * 576 + 512;
  int i = lane & 31;
  float inv = powf(10000.f, -(float)i / 32.f);
  float ang = (float)s * inv;
  float sn, cs;
  sincosf(ang, &sn, &cs);
  float t1 = src[i], t2 = src[32 + i];
  float v = (lane < 32) ? (t1 * cs - t2 * sn) : (t2 * cs + t1 * sn);
  unsigned short bv = f2bf(v);
#pragma unroll
  for (int h = 0; h < HH; ++h)
    kf[(((long)(b * HH + h)) * SS + s) * 192 + 128 + lane] = bv;
}

// ---------------- kvu (NROWS,4096) f32 -> kf nope + vt (B*H,128,S) ----------------
__global__ __launch_bounds__(256) void k_extract_kv(const float* __restrict__ kvu,
                                                    unsigned short* __restrict__ kf,
                                                    unsigned short* __restrict__ vt) {
  __shared__ unsigned short vtile[64][132];
  int blk = blockIdx.x;
  int st = blk & 31;
  int h = (blk >> 5) & 15;
  int b = blk >> 9;
  int s0 = st * 64;
  long bh = (long)b * HH + h;
#pragma unroll
  for (int it = 0; it < 16; ++it) {
    int v4 = it * 256 + threadIdx.x;
    int sl = v4 >> 6;
    int c = (v4 & 63) * 4;
    float4 val = *(const float4*)&kvu[(((long)(b * SS + s0 + sl)) * HH + h) * 256 + c];
    ushort4 ov = { f2bf(val.x), f2bf(val.y), f2bf(val.z), f2bf(val.w) };
    if (c < 128) {
      *(ushort4*)&kf[(bh * SS + s0 + sl) * 192 + c] = ov;
    } else {
      *(ushort4*)&vtile[sl][c - 128] = ov;
    }
  }
  __syncthreads();
#pragma unroll
  for (int it = 0; it < 32; ++it) {
    int e = it * 256 + threadIdx.x;
    int d = e >> 6, sl = e & 63;
    vt[(bh * 128 + d) * SS + s0 + sl] = vtile[sl][d];
  }
}

// ---------------- flash attention ----------------
__global__ __launch_bounds__(256) void k_attn(const unsigned short* __restrict__ qf,
                                              const unsigned short* __restrict__ kf,
                                              const unsigned short* __restrict__ vt,
                                              unsigned short* __restrict__ o) {
  __shared__ unsigned short kbuf[64 * 200];        // row stride 400B
  __shared__ unsigned short pbuf[4][16 * 72];      // per-wave P, row stride 144B
  int qt = blockIdx.x & 31;                        // S/64 = 32 q-tiles
  int bh = blockIdx.x >> 5;
  int q0 = qt * 64;
  int wave = threadIdx.x >> 6, lane = threadIdx.x & 63;
  int l15 = lane & 15, lhi = lane >> 4;

  const unsigned short* Qb = qf + ((long)bh * SS + q0 + wave * 16 + l15) * 192 + lhi * 8;
  bf16x8 qfr[6];
#pragma unroll
  for (int ks = 0; ks < 6; ++ks) qfr[ks] = *(const bf16x8*)(Qb + ks * 32);

  float m[4], lsum[4];
#pragma unroll
  for (int j = 0; j < 4; ++j) { m[j] = -1e30f; lsum[j] = 0.f; }
  f32x4 accO[8] = {};

  int nt = q0 / 64 + 1;
  for (int t = 0; t < nt; ++t) {
    int kv0 = t * 64;
    __syncthreads();
#pragma unroll
    for (int c = 0; c < 6; ++c) {
      int chunk = c * 256 + threadIdx.x;
      int r = chunk / 24, cc = (chunk % 24) * 8;
      *(uint4*)&kbuf[r * 200 + cc] =
          *(const uint4*)&kf[((long)bh * SS + kv0 + r) * 192 + cc];
    }
    __syncthreads();
    f32x4 sc[4] = {};
#pragma unroll
    for (int ks = 0; ks < 6; ++ks) {
#pragma unroll
      for (int nf = 0; nf < 4; ++nf) {
        bf16x8 kfr = *(const bf16x8*)&kbuf[(nf * 16 + l15) * 200 + ks * 32 + lhi * 8];
        sc[nf] = mfma16(qfr[ks], kfr, sc[nf]);
      }
    }
    bool lastt = (t == nt - 1);
    float alpha[4];
#pragma unroll
    for (int j = 0; j < 4; ++j) {
      int rowg = q0 + wave * 16 + lhi * 4 + j;
      if (lastt) {
#pragma unroll
        for (int nf = 0; nf < 4; ++nf)
          if (kv0 + nf * 16 + l15 > rowg) sc[nf][j] = -1e30f;
      }
      float mx = fmaxf(fmaxf(sc[0][j], sc[1][j]), fmaxf(sc[2][j], sc[3][j]));
#pragma unroll
      for (int off = 1; off < 16; off <<= 1) mx = fmaxf(mx, __shfl_xor(mx, off));
      float mn = fmaxf(m[j], mx);
      alpha[j] = __expf(m[j] - mn);
      m[j] = mn;
      float ps = 0.f;
#pragma unroll
      for (int nf = 0; nf < 4; ++nf) {
        float p = __expf(sc[nf][j] - mn);
        sc[nf][j] = p;
        ps += p;
      }
#pragma unroll
      for (int off = 1; off < 16; off <<= 1) ps += __shfl_xor(ps, off);
      lsum[j] = lsum[j] * alpha[j] + ps;
    }
#pragma unroll
    for (int d = 0; d < 8; ++d)
#pragma unroll
      for (int j = 0; j < 4; ++j) accO[d][j] *= alpha[j];
    // P -> per-wave LDS (bf16), then read back in A-frag layout
#pragma unroll
    for (int nf = 0; nf < 4; ++nf)
#pragma unroll
      for (int j = 0; j < 4; ++j)
        pbuf[wave][(lhi * 4 + j) * 72 + nf * 16 + l15] = f2bf(sc[nf][j]);
    asm volatile("s_waitcnt lgkmcnt(0)" ::: "memory");
#pragma unroll
    for (int kk = 0; kk < 2; ++kk) {
      bf16x8 pa = *(const bf16x8*)&pbuf[wave][l15 * 72 + kk * 32 + lhi * 8];
#pragma unroll
      for (int nf = 0; nf < 8; ++nf) {
        bf16x8 vb = *(const bf16x8*)&vt[((long)bh * 128 + nf * 16 + l15) * SS +
                                        kv0 + kk * 32 + lhi * 8];
        accO[nf] = mfma16(pa, vb, accO[nf]);
      }
    }
  }
  int b = bh >> 4, h = bh & 15;
  float inv[4];
#pragma unroll
  for (int j = 0; j < 4; ++j) inv[j] = 1.f / lsum[j];
#pragma unroll
  for (int nf = 0; nf < 8; ++nf)
#pragma unroll
    for (int j = 0; j < 4; ++j) {
      long sr = q0 + wave * 16 + lhi * 4 + j;
      o[((long)b * SS + sr) * 2048 + h * 128 + nf * 16 + l15] = f2bf(accO[nf][j] * inv[j]);
    }
}

extern "C" void kernel_launch(void* const* d_in, const int* in_sizes, int n_in,
                              void* d_out, int out_size, void* d_ws, size_t ws_size,
                              hipStream_t stream) {
  const float* x    = (const float*)d_in[0];
  const float* wqd  = (const float*)d_in[1];
  const float* bqd  = (const float*)d_in[2];
  const float* qnw  = (const float*)d_in[3];
  const float* wqu  = (const float*)d_in[4];
  const float* bqu  = (const float*)d_in[5];
  const float* wkvd = (const float*)d_in[6];
  const float* bkvd = (const float*)d_in[7];
  const float* kvnw = (const float*)d_in[8];
  const float* wkvu = (const float*)d_in[9];
  const float* bkvu = (const float*)d_in[10];
  const float* wout = (const float*)d_in[11];
  const float* bout = (const float*)d_in[12];
  float* out = (float*)d_out;

  char* ws = (char*)d_ws;
  size_t off = 0;
  auto alloc = [&](size_t sz) {
    char* p = ws + off;
    off += (sz + 255) & ~(size_t)255;
    return p;
  };
  unsigned short* xb    = (unsigned short*)alloc((size_t)NROWS * 2048 * 2);
  unsigned short* wqdt  = (unsigned short*)alloc((size_t)1536 * 2048 * 2);
  unsigned short* wqut  = (unsigned short*)alloc((size_t)3072 * 1536 * 2);
  unsigned short* wkvdt = (unsigned short*)alloc((size_t)640 * 2048 * 2);
  unsigned short* wkvut = (unsigned short*)alloc((size_t)4096 * 512 * 2);
  unsigned short* woutt = (unsigned short*)alloc((size_t)2048 * 2048 * 2);
  unsigned short* qn    = (unsigned short*)alloc((size_t)NROWS * 1536 * 2);
  unsigned short* kvn   = (unsigned short*)alloc((size_t)NROWS * 512 * 2);
  unsigned short* qfb   = (unsigned short*)alloc((size_t)32 * SS * 192 * 2);
  unsigned short* kfb   = (unsigned short*)alloc((size_t)32 * SS * 192 * 2);
  unsigned short* vtb   = (unsigned short*)alloc((size_t)32 * 128 * SS * 2);
  unsigned short* ob    = (unsigned short*)alloc((size_t)NROWS * 2048 * 2);
  float* sA = (float*)alloc((size_t)NROWS * 1536 * 4);   // qd, then kvd
  float* sB = (float*)alloc((size_t)NROWS * 4096 * 4);   // q,  then kvu

  // conversions
  k_convert<<<2048, 256, 0, stream>>>(x, xb, (long)NROWS * 2048 / 4);
  k_transpose<<<dim3(48, 64), 256, 0, stream>>>(wqd, wqdt, 2048, 1536, 1536);
  k_transpose<<<dim3(96, 48), 256, 0, stream>>>(wqu, wqut, 1536, 3072, 3072);
  k_transpose<<<dim3(20, 64), 256, 0, stream>>>(wkvd, wkvdt, 2048, 576, 640);
  k_transpose<<<dim3(128, 16), 256, 0, stream>>>(wkvu, wkvut, 512, 4096, 4096);
  k_transpose<<<dim3(64, 64), 256, 0, stream>>>(wout, woutt, 2048, 2048, 2048);

  // q path
  k_gemm<<<32 * 12, 256, 0, stream>>>(xb, wqdt, bqd, sA, NROWS, 1536, 2048);
  k_rmsnorm<<<NROWS, 256, 0, stream>>>(sA, qnw, qn, 1536, 1536);
  k_gemm<<<32 * 24, 256, 0, stream>>>(qn, wqut, bqu, sB, NROWS, 3072, 1536);
  k_extract_q<<<NROWS * HH / 4, 256, 0, stream>>>(sB, qfb);

  // kv path
  k_gemm<<<32 * 5, 256, 0, stream>>>(xb, wkvdt, bkvd, sA, NROWS, 576, 2048);
  k_rmsnorm<<<NROWS, 256, 0, stream>>>(sA, kvnw, kvn, 512, 576);
  k_extract_krope<<<NROWS, 64, 0, stream>>>(sA, kfb);
  k_gemm<<<32 * 32, 256, 0, stream>>>(kvn, wkvut, bkvu, sB, NROWS, 4096, 512);
  k_extract_kv<<<1024, 256, 0, stream>>>(sB, kfb, vtb);

  // attention
  k_attn<<<1024, 256, 0, stream>>>(qfb, kfb, vtb, ob);

  // output projection
  k_gemm<<<32 * 16, 256, 0, stream>>>(ob, woutt, bout, out, NROWS, 2048, 2048);
}

// Round 2
// 532.720 us; speedup vs baseline: 1.4900x; 1.4900x over previous
//
#include <hip/hip_runtime.h>
#include <hip/hip_bf16.h>
#include <math.h>

#define HH 16
#define SS 2048
#define BBATCH 2
#define NROWS 4096   // B*S

typedef __attribute__((ext_vector_type(8))) __bf16 bf16x8;
typedef __attribute__((ext_vector_type(4))) float f32x4;
typedef const __attribute__((address_space(1))) unsigned int* gas1_t;
typedef __attribute__((address_space(3))) unsigned int* las3_t;

__device__ __forceinline__ unsigned short f2bf(float f) {
  unsigned u = __builtin_bit_cast(unsigned, f);
  u += 0x7fffu + ((u >> 16) & 1u);
  return (unsigned short)(u >> 16);
}

__device__ __forceinline__ void gload16(const void* g, void* l) {
  __builtin_amdgcn_global_load_lds((gas1_t)g, (las3_t)l, 16, 0, 0);
}
__device__ __forceinline__ f32x4 mfma16(bf16x8 a, bf16x8 b, f32x4 c) {
  return __builtin_amdgcn_mfma_f32_16x16x32_bf16(a, b, c, 0, 0, 0);
}

// ---------------- f32 -> bf16 copy (same layout) ----------------
__global__ __launch_bounds__(256) void k_convert(const float* __restrict__ in,
                                                 unsigned short* __restrict__ out, long n4) {
  long i = (long)blockIdx.x * blockDim.x + threadIdx.x;
  long stride = (long)gridDim.x * blockDim.x;
  for (; i < n4; i += stride) {
    float4 v = ((const float4*)in)[i];
    ushort4 o = { f2bf(v.x), f2bf(v.y), f2bf(v.z), f2bf(v.w) };
    ((ushort4*)out)[i] = o;
  }
}

// ---------------- W (K,N) f32 -> Wt (Npad,K) bf16 ----------------
__global__ __launch_bounds__(256) void k_transpose(const float* __restrict__ W,
                                                   unsigned short* __restrict__ Wt,
                                                   int K, int N, int Npad) {
  __shared__ float tile[32][33];
  int n0 = blockIdx.x * 32, k0 = blockIdx.y * 32;
  int tx = threadIdx.x & 31, ty = threadIdx.x >> 5;
  for (int i = ty; i < 32; i += 8) {
    int k = k0 + i, n = n0 + tx;
    tile[i][tx] = (k < K && n < N) ? W[(long)k * N + n] : 0.f;
  }
  __syncthreads();
  for (int i = ty; i < 32; i += 8) {
    int n = n0 + i, k = k0 + tx;
    if (n < Npad && k < K) Wt[(long)n * K + k] = f2bf(tile[tx][i]);
  }
}

// ---------------- GEMM: C(M,N) f32 = A(M,K)bf16 * Bt(Npad,K)bf16 + bias ----------------
__global__ __launch_bounds__(256) void k_gemm(const unsigned short* __restrict__ A,
                                              const unsigned short* __restrict__ Bt,
                                              const float* __restrict__ bias,
                                              float* __restrict__ C,
                                              int M, int N, int K) {
  __shared__ unsigned short lA[128 * 32];
  __shared__ unsigned short lB[128 * 32];
  int tid = threadIdx.x;
  int wave = tid >> 6, lane = tid & 63;
  int l15 = lane & 15, lhi = lane >> 4;
  int ntn = (N + 127) >> 7;
  int tm = blockIdx.x / ntn, tn = blockIdx.x % ntn;
  long row0 = (long)tm * 128, col0 = (long)tn * 128;
  int wr = wave >> 1, wc = wave & 1;

  const unsigned short* gA = A + (row0 + (tid >> 2)) * K + (tid & 3) * 8;
  const unsigned short* gB = Bt + (col0 + (tid >> 2)) * K + (tid & 3) * 8;
  unsigned short* lA0 = &lA[tid * 8];
  unsigned short* lB0 = &lB[tid * 8];

  f32x4 acc[4][4] = {};
  for (int k0 = 0; k0 < K; k0 += 32) {
    __syncthreads();
    gload16(gA + k0, lA0);
    gload16(gA + (long)64 * K + k0, lA0 + 2048);
    gload16(gB + k0, lB0);
    gload16(gB + (long)64 * K + k0, lB0 + 2048);
    asm volatile("s_waitcnt vmcnt(0)" ::: "memory");
    __syncthreads();
    bf16x8 af[4], bfr[4];
#pragma unroll
    for (int i = 0; i < 4; ++i) {
      af[i]  = *(const bf16x8*)&lA[(wr * 64 + i * 16 + l15) * 32 + lhi * 8];
      bfr[i] = *(const bf16x8*)&lB[(wc * 64 + i * 16 + l15) * 32 + lhi * 8];
    }
#pragma unroll
    for (int i = 0; i < 4; ++i)
#pragma unroll
      for (int j = 0; j < 4; ++j)
        acc[i][j] = mfma16(af[i], bfr[j], acc[i][j]);
  }
#pragma unroll
  for (int i = 0; i < 4; ++i)
#pragma unroll
    for (int j = 0; j < 4; ++j) {
      long r = row0 + wr * 64 + i * 16 + lhi * 4;
      long c = col0 + wc * 64 + j * 16 + l15;
      if (c < N) {
        float bv = bias[c];
#pragma unroll
        for (int rr = 0; rr < 4; ++rr)
          C[(r + rr) * N + c] = acc[i][j][rr] + bv;
      }
    }
}

// ---------------- RMSNorm: f32 (rows, ldx) -> bf16 (rows, L) ----------------
__global__ __launch_bounds__(256) void k_rmsnorm(const float* __restrict__ X,
                                                 const float* __restrict__ w,
                                                 unsigned short* __restrict__ Y,
                                                 int L, int ldx) {
  long row = blockIdx.x;
  const float* x = X + row * ldx;
  float ss = 0.f;
  int n4 = L >> 2;
  for (int i = threadIdx.x; i < n4; i += 256) {
    float4 v = ((const float4*)x)[i];
    ss += v.x * v.x + v.y * v.y + v.z * v.z + v.w * v.w;
  }
  for (int off = 32; off > 0; off >>= 1) ss += __shfl_xor(ss, off);
  __shared__ float sb[4];
  if ((threadIdx.x & 63) == 0) sb[threadIdx.x >> 6] = ss;
  __syncthreads();
  float scale = rsqrtf((sb[0] + sb[1] + sb[2] + sb[3]) / (float)L + 1e-6f);
  unsigned short* y = Y + row * L;
  for (int i = threadIdx.x; i < L; i += 256)
    y[i] = f2bf(x[i] * scale * w[i]);
}

// ---------------- q (NROWS,3072) f32 -> qf (B*H, S, 192) bf16, rope+scale ----------------
// scale includes log2(e) so attention softmax runs in exp2 domain
__global__ __launch_bounds__(256) void k_extract_q(const float* __restrict__ q,
                                                   unsigned short* __restrict__ qf) {
  int idx = blockIdx.x * 4 + (threadIdx.x >> 6);   // (b*S+s)*H + h
  int lane = threadIdx.x & 63;
  int h = idx & 15;
  int bs = idx >> 4;
  int s = bs & (SS - 1);
  const float* src = q + (long)idx * 192;
  long bh = (long)(bs >> 11) * HH + h;
  unsigned short* dst = qf + (bh * SS + s) * 192;
  const float scq = 0.07216878364870322f * 1.4426950408889634f;  // 192^-0.5 * log2(e)
  dst[lane]      = f2bf(src[lane] * scq);
  dst[lane + 64] = f2bf(src[lane + 64] * scq);
  if (lane < 32) {
    float inv = powf(10000.f, -(float)lane / 32.f);
    float ang = (float)s * inv;
    float sn, cs;
    sincosf(ang, &sn, &cs);
    float t1 = src[128 + lane], t2 = src[160 + lane];
    dst[128 + lane] = f2bf((t1 * cs - t2 * sn) * scq);
    dst[160 + lane] = f2bf((t2 * cs + t1 * sn) * scq);
  }
}

// ---------------- kvd rope cols -> kf[...,128:192] broadcast, XOR-swizzled ----------------
__global__ __launch_bounds__(64) void k_extract_krope(const float* __restrict__ kvd,
                                                      unsigned short* __restrict__ kf) {
  int bs = blockIdx.x;
  int lane = threadIdx.x;
  int s = bs & (SS - 1), b = bs >> 11;
  const float* src = kvd + (long)bs * 576 + 512;
  int i = lane & 31;
  float inv = powf(10000.f, -(float)i / 32.f);
  float ang = (float)s * inv;
  float sn, cs;
  sincosf(ang, &sn, &cs);
  float t1 = src[i], t2 = src[32 + i];
  float v = (lane < 32) ? (t1 * cs - t2 * sn) : (t2 * cs + t1 * sn);
  unsigned short bv = f2bf(v);
  int col = (128 + lane) ^ ((s & 7) << 3);   // pre-swizzle for LDS bank spread
#pragma unroll
  for (int h = 0; h < HH; ++h)
    kf[(((long)(b * HH + h)) * SS + s) * 192 + col] = bv;
}

// ---------------- kvu (NROWS,4096) f32 -> kf nope (swizzled) + vt (B*H,128,S) ----------------
__global__ __launch_bounds__(256) void k_extract_kv(const float* __restrict__ kvu,
                                                    unsigned short* __restrict__ kf,
                                                    unsigned short* __restrict__ vt) {
  __shared__ unsigned short vtile[64][132];
  int blk = blockIdx.x;
  int st = blk & 31;
  int h = (blk >> 5) & 15;
  int b = blk >> 9;
  int s0 = st * 64;
  long bh = (long)b * HH + h;
#pragma unroll
  for (int it = 0; it < 16; ++it) {
    int v4 = it * 256 + threadIdx.x;
    int sl = v4 >> 6;
    int c = (v4 & 63) * 4;
    int s = s0 + sl;
    float4 val = *(const float4*)&kvu[(((long)(b * SS + s)) * HH + h) * 256 + c];
    ushort4 ov = { f2bf(val.x), f2bf(val.y), f2bf(val.z), f2bf(val.w) };
    if (c < 128) {
      *(ushort4*)&kf[(bh * SS + s) * 192 + (c ^ ((s & 7) << 3))] = ov;
    } else {
      *(ushort4*)&vtile[sl][c - 128] = ov;
    }
  }
  __syncthreads();
#pragma unroll
  for (int it = 0; it < 32; ++it) {
    int e = it * 256 + threadIdx.x;
    int d = e >> 6, sl = e & 63;
    vt[(bh * 128 + d) * SS + s0 + sl] = vtile[sl][d];
  }
}

// ---------------- flash attention: swapped-QK^T, in-register softmax ----------------
// Block: 4 waves, each wave owns 16 q-rows; block processes q-tile pair {31-p, p}
// (uniform 33 KV-iterations). K double-buffered in LDS via linear global_load_lds
// of the pre-swizzled kf; V read direct from global (L2-resident).
__global__ __launch_bounds__(256) void k_attn(const unsigned short* __restrict__ qf,
                                              const unsigned short* __restrict__ kf,
                                              const unsigned short* __restrict__ vt,
                                              unsigned short* __restrict__ o) {
  __shared__ unsigned short kbuf[2][64 * 192];   // 2 x 24KB, linear, XOR-swizzled content
  __shared__ unsigned short pbuf[4][16 * 72];    // per-wave P (16q x 64k), stride 72
  int tid = threadIdx.x;
  int wave = tid >> 6, lane = tid & 63;
  int l15 = lane & 15, lhi = lane >> 4;
  int pair = blockIdx.x & 15;
  int bh = blockIdx.x >> 4;
  int b = bh >> 4, h = bh & 15;
  const char* kbase = (const char*)(kf + (long)bh * SS * 192);

  int qts[2] = { 31 - pair, pair };
  for (int qi = 0; qi < 2; ++qi) {
    int qt = qts[qi];
    int q0 = qt * 64;
    int nt = qt + 1;

    // Q fragments (B-operand): lane holds Q[q0+wave*16+l15][k-chunk]
    const unsigned short* Qb = qf + ((long)bh * SS + q0 + wave * 16 + l15) * 192 + lhi * 8;
    bf16x8 qfr[6];
#pragma unroll
    for (int ks = 0; ks < 6; ++ks) qfr[ks] = *(const bf16x8*)(Qb + ks * 32);

    float m = -3e38f, lsum = 0.f;
    f32x4 accO[8] = {};

    // prologue: stage tile 0 into buf 0
    {
      const char* src = kbase;
      char* dst = (char*)&kbuf[0][0];
#pragma unroll
      for (int p = 0; p < 6; ++p)
        gload16(src + p * 4096 + tid * 16, dst + p * 4096 + tid * 16);
    }
    asm volatile("s_waitcnt vmcnt(0)" ::: "memory");
    __syncthreads();

    for (int t = 0; t < nt; ++t) {
      int kv0 = t * 64;
      // stage next tile (overlaps with this tile's compute)
      if (t + 1 < nt) {
        const char* src = kbase + (long)(kv0 + 64) * 384;
        char* dst = (char*)&kbuf[(t + 1) & 1][0];
#pragma unroll
        for (int p = 0; p < 6; ++p)
          gload16(src + p * 4096 + tid * 16, dst + p * 4096 + tid * 16);
      }
      const char* kb = (const char*)&kbuf[t & 1][0];

      // QK^T (swapped): sc[nf] = S^T tile, rows k=nf*16+lhi*4+j, col q=l15
      f32x4 sc[4] = {};
#pragma unroll
      for (int ks = 0; ks < 6; ++ks) {
#pragma unroll
        for (int nf = 0; nf < 4; ++nf) {
          int r = nf * 16 + l15;
          int cb = ks * 64 + lhi * 16;
          bf16x8 kfrag = *(const bf16x8*)(kb + r * 384 + (cb ^ ((r & 7) << 4)));
          sc[nf] = mfma16(kfrag, qfr[ks], sc[nf]);
        }
      }

      // online softmax, fully lane-local over k except 2+2 shfl
      bool diag = (t == nt - 1);
      int qin = wave * 16 + l15;
      float mx = -3e38f;
#pragma unroll
      for (int nf = 0; nf < 4; ++nf)
#pragma unroll
        for (int j = 0; j < 4; ++j) {
          if (diag) {
            int kin = nf * 16 + lhi * 4 + j;
            if (kin > qin) sc[nf][j] = -3e38f;
          }
          mx = fmaxf(mx, sc[nf][j]);
        }
      mx = fmaxf(mx, __shfl_xor(mx, 16));
      mx = fmaxf(mx, __shfl_xor(mx, 32));
      float mn = fmaxf(m, mx);
      float alpha = exp2f(m - mn);
      m = mn;
      float ps = 0.f;
#pragma unroll
      for (int nf = 0; nf < 4; ++nf)
#pragma unroll
        for (int j = 0; j < 4; ++j) {
          float pv = exp2f(sc[nf][j] - mn);
          sc[nf][j] = pv;
          ps += pv;
        }
      ps += __shfl_xor(ps, 16);
      ps += __shfl_xor(ps, 32);
      lsum = lsum * alpha + ps;
#pragma unroll
      for (int nf = 0; nf < 8; ++nf)
#pragma unroll
        for (int j = 0; j < 4; ++j) accO[nf][j] *= alpha;

      // P (bf16) -> per-wave LDS, row q=l15, cols k
      unsigned short* pw = &pbuf[wave][l15 * 72 + lhi * 4];
#pragma unroll
      for (int nf = 0; nf < 4; ++nf) {
        ushort4 pk = { f2bf(sc[nf][0]), f2bf(sc[nf][1]), f2bf(sc[nf][2]), f2bf(sc[nf][3]) };
        *(ushort4*)(pw + nf * 16) = pk;
      }
      __builtin_amdgcn_s_waitcnt(0);  // lgkmcnt(0) implied by compiler dep; cheap safety

      // PV: accO[nf] += V^T-frag x P^T-frag  (O^T: rows d, col q)
#pragma unroll
      for (int kk = 0; kk < 2; ++kk) {
        bf16x8 pfrag = *(const bf16x8*)&pbuf[wave][l15 * 72 + kk * 32 + lhi * 8];
#pragma unroll
        for (int nf = 0; nf < 8; ++nf) {
          bf16x8 vfrag = *(const bf16x8*)&vt[((long)bh * 128 + nf * 16 + l15) * SS +
                                             kv0 + kk * 32 + lhi * 8];
          accO[nf] = mfma16(vfrag, pfrag, accO[nf]);
        }
      }
      asm volatile("s_waitcnt vmcnt(0)" ::: "memory");
      __syncthreads();
    }

    // store O^T frags: lane has q=l15 row, d = nf*16+lhi*4+j -> 8B stores
    float invl = 1.f / lsum;
    long orow = (long)b * SS + q0 + wave * 16 + l15;
#pragma unroll
    for (int nf = 0; nf < 8; ++nf) {
      ushort4 ov = { f2bf(accO[nf][0] * invl), f2bf(accO[nf][1] * invl),
                     f2bf(accO[nf][2] * invl), f2bf(accO[nf][3] * invl) };
      *(ushort4*)&o[orow * 2048 + h * 128 + nf * 16 + lhi * 4] = ov;
    }
  }
}

extern "C" void kernel_launch(void* const* d_in, const int* in_sizes, int n_in,
                              void* d_out, int out_size, void* d_ws, size_t ws_size,
                              hipStream_t stream) {
  const float* x    = (const float*)d_in[0];
  const float* wqd  = (const float*)d_in[1];
  const float* bqd  = (const float*)d_in[2];
  const float* qnw  = (const float*)d_in[3];
  const float* wqu  = (const float*)d_in[4];
  const float* bqu  = (const float*)d_in[5];
  const float* wkvd = (const float*)d_in[6];
  const float* bkvd = (const float*)d_in[7];
  const float* kvnw = (const float*)d_in[8];
  const float* wkvu = (const float*)d_in[9];
  const float* bkvu = (const float*)d_in[10];
  const float* wout = (const float*)d_in[11];
  const float* bout = (const float*)d_in[12];
  float* out = (float*)d_out;

  char* ws = (char*)d_ws;
  size_t off = 0;
  auto alloc = [&](size_t sz) {
    char* p = ws + off;
    off += (sz + 255) & ~(size_t)255;
    return p;
  };
  unsigned short* xb    = (unsigned short*)alloc((size_t)NROWS * 2048 * 2);
  unsigned short* wqdt  = (unsigned short*)alloc((size_t)1536 * 2048 * 2);
  unsigned short* wqut  = (unsigned short*)alloc((size_t)3072 * 1536 * 2);
  unsigned short* wkvdt = (unsigned short*)alloc((size_t)640 * 2048 * 2);
  unsigned short* wkvut = (unsigned short*)alloc((size_t)4096 * 512 * 2);
  unsigned short* woutt = (unsigned short*)alloc((size_t)2048 * 2048 * 2);
  unsigned short* qn    = (unsigned short*)alloc((size_t)NROWS * 1536 * 2);
  unsigned short* kvn   = (unsigned short*)alloc((size_t)NROWS * 512 * 2);
  unsigned short* qfb   = (unsigned short*)alloc((size_t)32 * SS * 192 * 2);
  unsigned short* kfb   = (unsigned short*)alloc((size_t)32 * SS * 192 * 2);
  unsigned short* vtb   = (unsigned short*)alloc((size_t)32 * 128 * SS * 2);
  unsigned short* ob    = (unsigned short*)alloc((size_t)NROWS * 2048 * 2);
  float* sA = (float*)alloc((size_t)NROWS * 1536 * 4);   // qd, then kvd
  float* sB = (float*)alloc((size_t)NROWS * 4096 * 4);   // q,  then kvu

  // conversions
  k_convert<<<2048, 256, 0, stream>>>(x, xb, (long)NROWS * 2048 / 4);
  k_transpose<<<dim3(48, 64), 256, 0, stream>>>(wqd, wqdt, 2048, 1536, 1536);
  k_transpose<<<dim3(96, 48), 256, 0, stream>>>(wqu, wqut, 1536, 3072, 3072);
  k_transpose<<<dim3(20, 64), 256, 0, stream>>>(wkvd, wkvdt, 2048, 576, 640);
  k_transpose<<<dim3(128, 16), 256, 0, stream>>>(wkvu, wkvut, 512, 4096, 4096);
  k_transpose<<<dim3(64, 64), 256, 0, stream>>>(wout, woutt, 2048, 2048, 2048);

  // q path
  k_gemm<<<32 * 12, 256, 0, stream>>>(xb, wqdt, bqd, sA, NROWS, 1536, 2048);
  k_rmsnorm<<<NROWS, 256, 0, stream>>>(sA, qnw, qn, 1536, 1536);
  k_gemm<<<32 * 24, 256, 0, stream>>>(qn, wqut, bqu, sB, NROWS, 3072, 1536);
  k_extract_q<<<NROWS * HH / 4, 256, 0, stream>>>(sB, qfb);

  // kv path
  k_gemm<<<32 * 5, 256, 0, stream>>>(xb, wkvdt, bkvd, sA, NROWS, 576, 2048);
  k_rmsnorm<<<NROWS, 256, 0, stream>>>(sA, kvnw, kvn, 512, 576);
  k_extract_krope<<<NROWS, 64, 0, stream>>>(sA, kfb);
  k_gemm<<<32 * 32, 256, 0, stream>>>(kvn, wkvut, bkvu, sB, NROWS, 4096, 512);
  k_extract_kv<<<1024, 256, 0, stream>>>(sB, kfb, vtb);

  // attention (512 blocks: 32 bh x 16 q-tile pairs, uniform work)
  k_attn<<<512, 256, 0, stream>>>(qfb, kfb, vtb, ob);

  // output projection
  k_gemm<<<32 * 16, 256, 0, stream>>>(ob, woutt, bout, out, NROWS, 2048, 2048);
}